// Round 5
// baseline (1203.493 us; speedup 1.0000x reference)
//
#include <hip/hip_runtime.h>
#include <hip/hip_bf16.h>
#include <math.h>

// ---------- types / helpers ----------
typedef short    short8  __attribute__((ext_vector_type(8)));
typedef float    floatx4 __attribute__((ext_vector_type(4)));

__device__ __forceinline__ float b2f(unsigned short u) {
    union { float f; unsigned int i; } v; v.i = ((unsigned int)u) << 16; return v.f;
}
__device__ __forceinline__ unsigned short f2b(float f) {
    union { float f; unsigned int i; } v; v.f = f;
    unsigned int b = v.i;
    return (unsigned short)((b + 0x7FFFu + ((b >> 16) & 1u)) >> 16);
}
// dual-dtype read: element i of input tensor that is bf16 (flag=0) or f32 (flag=1)
__device__ __forceinline__ float rd(const void* p, long i, int f) {
    return f ? ((const float*)p)[i] : b2f(((const unsigned short*)p)[i]);
}
// fast GELU (tanh form, |err|<~3e-3; erff epilogue was ~half of fw1 kernel cycles)
__device__ __forceinline__ float fgelu(float x) {
    float u = 0.7978845608f * x * (1.f + 0.044715f * x * x);
    float e = __expf(-2.f * fabsf(u));
    float th = 1.f - 2.f * e / (1.f + e);
    th = (u < 0.f) ? -th : th;
    return 0.5f * x * (1.f + th);
}

#define NTOK_ 50176   // 16*56*56

// ---------- dtype detector: bf16 N(0,1) never has exp>=0x90; f32 misread does ----------
__global__ __launch_bounds__(256) void k_detect(const unsigned short* __restrict__ x,
                                                int* __restrict__ flag) {
    __shared__ int cnt;
    if (threadIdx.x == 0) cnt = 0;
    __syncthreads();
    unsigned short v = x[threadIdx.x];
    int e = (v >> 7) & 0xFF;
    if (e >= 0x90) atomicAdd(&cnt, 1);
    __syncthreads();
    if (threadIdx.x == 0) *flag = (cnt >= 8) ? 1 : 0;
}

// ---------- xm = x + spe -> fp32 ----------
__global__ __launch_bounds__(256) void k_add_spe(const void* __restrict__ x,
                                                 const void* __restrict__ spe,
                                                 float* __restrict__ xm,
                                                 const int* __restrict__ flagp) {
    const int f = *flagp;
    long i = ((long)blockIdx.x * 256 + threadIdx.x) * 4;
    float4 o;
    if (f) {
        float4 a = *(const float4*)((const float*)x + i);
        float4 b = *(const float4*)((const float*)spe + i);
        o.x = a.x + b.x; o.y = a.y + b.y; o.z = a.z + b.z; o.w = a.w + b.w;
    } else {
        ushort4 a = *(const ushort4*)((const unsigned short*)x + i);
        ushort4 b = *(const ushort4*)((const unsigned short*)spe + i);
        o.x = b2f(a.x) + b2f(b.x); o.y = b2f(a.y) + b2f(b.y);
        o.z = b2f(a.z) + b2f(b.z); o.w = b2f(a.w) + b2f(b.w);
    }
    *(float4*)(xm + i) = o;
}

// ---------- weight transpose: (K,N) -> (N,K) bf16 ----------
__global__ __launch_bounds__(256) void k_transpose(const void* __restrict__ in, long ioff,
                                                   unsigned short* __restrict__ out,
                                                   int K, int N,
                                                   const int* __restrict__ flagp) {
    const int f = *flagp;
    int i = blockIdx.x * 256 + threadIdx.x;
    if (i >= K * N) return;
    int k = i / N, n = i - k * N;
    unsigned short o;
    if (f) o = f2b(((const float*)in)[ioff + i]);
    else   o = ((const unsigned short*)in)[ioff + i];   // bit-exact passthrough
    out[(long)n * K + k] = o;
}

// ---------- CPB table: relu(REL@cw1+cb1)@cw2+cb2 -> cpb[l][head][2401] ----------
__global__ __launch_bounds__(512) void k_cpb(const void* __restrict__ cw1,
                                             const void* __restrict__ cb1,
                                             const void* __restrict__ cw2,
                                             const void* __restrict__ cb2,
                                             float* __restrict__ cpb,
                                             const int* __restrict__ flagp) {
    const int f = *flagp;
    int p = blockIdx.x;      // pair index i*49+j
    int l = blockIdx.y;      // layer
    int t = threadIdx.x;     // 0..511
    int i = p / 49, j = p - i * 49;
    int yi = i / 7, xi = i - yi * 7, yj = j / 7, xj = j - yj * 7;
    float dy = (float)(yj - yi), dx = (float)(xj - xi);
    float sy = (dy > 0.f) ? 1.f : ((dy < 0.f) ? -1.f : 0.f);
    float sx = (dx > 0.f) ? 1.f : ((dx < 0.f) ? -1.f : 0.f);
    float r0 = sy * log1pf(fabsf(dy));
    float r1 = sx * log1pf(fabsf(dx));
    float h = r0 * rd(cw1, l * 1024 + t, f) + r1 * rd(cw1, l * 1024 + 512 + t, f)
            + rd(cb1, l * 512 + t, f);
    h = fmaxf(h, 0.f);
    __shared__ float red[512];
    for (int hh = 0; hh < 8; hh++) {
        red[t] = h * rd(cw2, (long)(l * 512 + t) * 8 + hh, f);
        __syncthreads();
        for (int s = 256; s > 0; s >>= 1) {
            if (t < s) red[t] += red[t + s];
            __syncthreads();
        }
        if (t == 0) cpb[((long)l * 8 + hh) * 2401 + p] = red[0] + rd(cb2, l * 8 + hh, f);
        __syncthreads();
    }
}

// ---------- cast (+roll) fp32 xm(group) -> bf16 xb(group) ----------
__global__ __launch_bounds__(256) void k_cast_roll(const float* __restrict__ xmg,
                                                   unsigned short* __restrict__ xb, int shift) {
    int gid = blockIdx.x * 256 + threadIdx.x;       // Mg*64 threads
    int c4 = (gid & 63) * 4;
    int t = gid >> 6;
    int x = t % 56; int t2 = t / 56;
    int y = t2 % 56;
    int b = t2 / 56;                                 // local batch in group
    int ys = y + shift; if (ys >= 56) ys -= 56;
    int xs = x + shift; if (xs >= 56) xs -= 56;
    float4 v = *(const float4*)(xmg + (((long)b * 3136 + ys * 56 + xs) * 256 + c4));
    ushort4 o; o.x = f2b(v.x); o.y = f2b(v.y); o.z = f2b(v.z); o.w = f2b(v.w);
    *(ushort4*)(xb + ((long)t * 256 + c4)) = o;
}

// ---------- MFMA GEMM: C[M,N] = A[M,K] @ Bt[N,K]^T (+bias)(+gelu) ----------
// flags: 1=bias, 2=gelu, 4=store bf16 (else fp32)
// bm on blockIdx.x (gridX multiple of 8): all bn-blocks of one bm share an XCD
// -> A tiles served from that XCD's L2 (round-4: bn-major cost 4x A over-fetch).
__global__ __launch_bounds__(256) void gemm_bt(const unsigned short* __restrict__ A,
                                               const unsigned short* __restrict__ Bt,
                                               const void* __restrict__ bias, long boff,
                                               void* __restrict__ Cp,
                                               int M, int N, int K, int flags,
                                               const int* __restrict__ flagp) {
    __shared__ __align__(16) unsigned short smem[16896];
    unsigned short* As = smem;            // 128 x 40
    unsigned short* Bs = smem + 5120;     // 128 x 40
    const int f = *flagp;
    const int tid = threadIdx.x;
    const int lane = tid & 63;
    const int wave = tid >> 6;
    const int wrow = (wave >> 1) * 64;
    const int wcol = (wave & 1) * 64;
    const int bm = blockIdx.x, bn = blockIdx.y;

    floatx4 acc[4][4] = {};

    const int arow = tid >> 2;       // 0..63
    const int aseg = (tid & 3) * 8;  // 0,8,16,24
    const unsigned short* Ag = A + (long)(bm * 128 + arow) * K + aseg;
    const unsigned short* Bg = Bt + (long)(bn * 128 + arow) * K + aseg;
    const long arow2 = (long)64 * K;

    const int q = lane >> 4;        // quad 0..3
    const int mrow = lane & 15;

    for (int k0 = 0; k0 < K; k0 += 32) {
        uint4 a0 = *(const uint4*)(Ag + k0);
        uint4 a1 = *(const uint4*)(Ag + k0 + arow2);
        uint4 b0 = *(const uint4*)(Bg + k0);
        uint4 b1 = *(const uint4*)(Bg + k0 + arow2);
        __syncthreads();
        *(uint4*)(As + arow * 40 + aseg) = a0;
        *(uint4*)(As + (arow + 64) * 40 + aseg) = a1;
        *(uint4*)(Bs + arow * 40 + aseg) = b0;
        *(uint4*)(Bs + (arow + 64) * 40 + aseg) = b1;
        __syncthreads();

        short8 af_[4], bf_[4];
#pragma unroll
        for (int mt = 0; mt < 4; mt++)
            af_[mt] = *(const short8*)(As + (wrow + mt * 16 + mrow) * 40 + q * 8);
#pragma unroll
        for (int nt = 0; nt < 4; nt++)
            bf_[nt] = *(const short8*)(Bs + (wcol + nt * 16 + mrow) * 40 + q * 8);
#pragma unroll
        for (int mt = 0; mt < 4; mt++)
#pragma unroll
            for (int nt = 0; nt < 4; nt++)
                acc[mt][nt] = __builtin_amdgcn_mfma_f32_16x16x32_bf16(af_[mt], bf_[nt], acc[mt][nt], 0, 0, 0);
    }

    __syncthreads();   // K-loop LDS reads complete before epilogue reuse

    if (flags & 4) {
        // ---- bf16 output: stage full 128x128 tile (row pad -> 132) ----
        unsigned short* T = smem;
#pragma unroll
        for (int nt = 0; nt < 4; nt++) {
            int col = wcol + nt * 16 + mrow;
            float bv = (flags & 1) ? rd(bias, boff + bn * 128 + col, f) : 0.f;
#pragma unroll
            for (int mt = 0; mt < 4; mt++) {
                int row0 = wrow + mt * 16 + q * 4;
#pragma unroll
                for (int r = 0; r < 4; r++) {
                    float v = acc[mt][nt][r] + bv;
                    if (flags & 2) v = fgelu(v);
                    T[(row0 + r) * 132 + col] = f2b(v);
                }
            }
        }
        __syncthreads();
        unsigned short* Cu = (unsigned short*)Cp;
        int row = tid >> 4;              // 0..15
        int col8 = (tid & 15) * 8;
#pragma unroll
        for (int p = 0; p < 8; p++) {
            int rr = p * 16 + row;
            *(uint4*)(Cu + (long)(bm * 128 + rr) * N + bn * 128 + col8) =
                *(const uint4*)(T + rr * 132 + col8);
        }
    } else {
        // ---- fp32 output: two 64-row halves through LDS ----
        float* Tf = (float*)smem;        // 64 x 132 floats
        float* Cf = (float*)Cp;
        float bvc[4];
#pragma unroll
        for (int nt = 0; nt < 4; nt++)
            bvc[nt] = (flags & 1) ? rd(bias, boff + bn * 128 + wcol + nt * 16 + mrow, f) : 0.f;
        int row = tid >> 5;              // 0..7
        int col4 = (tid & 31) * 4;
#pragma unroll
        for (int half = 0; half < 2; half++) {
            if (half) __syncthreads();
            if (wrow == half * 64) {
#pragma unroll
                for (int nt = 0; nt < 4; nt++) {
                    int col = wcol + nt * 16 + mrow;
#pragma unroll
                    for (int mt = 0; mt < 4; mt++) {
                        int lrow0 = mt * 16 + q * 4;
#pragma unroll
                        for (int r = 0; r < 4; r++) {
                            float v = acc[mt][nt][r] + bvc[nt];
                            if (flags & 2) v = fgelu(v);
                            Tf[(lrow0 + r) * 132 + col] = v;
                        }
                    }
                }
            }
            __syncthreads();
#pragma unroll
            for (int p = 0; p < 8; p++) {
                int rr = p * 8 + row;
                *(float4*)(Cf + (long)(bm * 128 + half * 64 + rr) * N + bn * 128 + col4) =
                    *(const float4*)(Tf + rr * 132 + col4);
            }
        }
    }
}

// ---------- fused GEMM(N=256) + PostNorm-LN + residual ----------
// t = A[64 rows, K] @ Bt[256,K]^T + bias; xm += LN(t)*g+bb; xb = bf16(xm).
// One block owns 64 full token rows -> A read exactly once chip-wide;
// replaces gemm_bt(proj/fw2) + k_ln_add (saves af fp32 roundtrip, 2 launches).
__global__ __launch_bounds__(256) void gemm_ln(const unsigned short* __restrict__ A,
                                               const unsigned short* __restrict__ Bt,
                                               const void* __restrict__ bias, long boff,
                                               const void* __restrict__ g, long goff,
                                               const void* __restrict__ bb, long b2off,
                                               float* __restrict__ xm,
                                               unsigned short* __restrict__ xb,
                                               int K,
                                               const int* __restrict__ flagp) {
    __shared__ __align__(16) unsigned short smem[17152];   // 34304 B (staging / Tf)
    __shared__ float pp[4][64][2];
    unsigned short* As = smem;            // 64 x 40
    unsigned short* Bs = smem + 2560;     // 256 x 40
    const int f = *flagp;
    const int tid = threadIdx.x;
    const int lane = tid & 63;
    const int wv = tid >> 6;
    const int wcol = wv * 64;
    const int bm = blockIdx.x;

    floatx4 acc[4][4] = {};
    const int arow = tid >> 2;       // 0..63
    const int aseg = (tid & 3) * 8;
    const unsigned short* Ag = A + (long)(bm * 64 + arow) * K + aseg;
    const unsigned short* Bg = Bt + (long)arow * K + aseg;
    const long brow2 = (long)64 * K;
    const int q = lane >> 4;
    const int c = lane & 15;

    for (int k0 = 0; k0 < K; k0 += 32) {
        uint4 a0 = *(const uint4*)(Ag + k0);
        uint4 b0 = *(const uint4*)(Bg + k0);
        uint4 b1 = *(const uint4*)(Bg + k0 + brow2);
        uint4 b2 = *(const uint4*)(Bg + k0 + 2 * brow2);
        uint4 b3 = *(const uint4*)(Bg + k0 + 3 * brow2);
        __syncthreads();
        *(uint4*)(As + arow * 40 + aseg) = a0;
        *(uint4*)(Bs + arow * 40 + aseg) = b0;
        *(uint4*)(Bs + (arow + 64) * 40 + aseg) = b1;
        *(uint4*)(Bs + (arow + 128) * 40 + aseg) = b2;
        *(uint4*)(Bs + (arow + 192) * 40 + aseg) = b3;
        __syncthreads();

        short8 af_[4], bf_[4];
#pragma unroll
        for (int mt = 0; mt < 4; mt++)
            af_[mt] = *(const short8*)(As + (mt * 16 + c) * 40 + q * 8);
#pragma unroll
        for (int nt = 0; nt < 4; nt++)
            bf_[nt] = *(const short8*)(Bs + (wcol + nt * 16 + c) * 40 + q * 8);
#pragma unroll
        for (int mt = 0; mt < 4; mt++)
#pragma unroll
            for (int nt = 0; nt < 4; nt++)
                acc[mt][nt] = __builtin_amdgcn_mfma_f32_16x16x32_bf16(af_[mt], bf_[nt], acc[mt][nt], 0, 0, 0);
    }
    __syncthreads();

    // ---- per-row sum / sumsq (bias included), cross-wave via LDS ----
    float bv[4];
#pragma unroll
    for (int nt = 0; nt < 4; nt++)
        bv[nt] = rd(bias, boff + wcol + nt * 16 + c, f);
#pragma unroll
    for (int mt = 0; mt < 4; mt++) {
#pragma unroll
        for (int r = 0; r < 4; r++) {
            float s1 = 0.f, s2 = 0.f;
#pragma unroll
            for (int nt = 0; nt < 4; nt++) {
                float v = acc[mt][nt][r] + bv[nt];
                s1 += v; s2 += v * v;
            }
            s1 += __shfl_xor(s1, 1); s2 += __shfl_xor(s2, 1);
            s1 += __shfl_xor(s1, 2); s2 += __shfl_xor(s2, 2);
            s1 += __shfl_xor(s1, 4); s2 += __shfl_xor(s2, 4);
            s1 += __shfl_xor(s1, 8); s2 += __shfl_xor(s2, 8);
            if (c == 0) {
                pp[wv][mt * 16 + q * 4 + r][0] = s1;
                pp[wv][mt * 16 + q * 4 + r][1] = s2;
            }
        }
    }
    __syncthreads();

    // ---- restage fp32 (stride 268 -> conflict-free) + coalesced LN apply ----
    float* Tf = (float*)smem;      // 32 x 268 fp32
#pragma unroll
    for (int half = 0; half < 2; half++) {
        if (half) __syncthreads();
#pragma unroll
        for (int mt2 = 0; mt2 < 2; mt2++) {
            int mt = half * 2 + mt2;
#pragma unroll
            for (int nt = 0; nt < 4; nt++)
#pragma unroll
                for (int r = 0; r < 4; r++)
                    Tf[(mt2 * 16 + q * 4 + r) * 268 + wcol + nt * 16 + c] = acc[mt][nt][r] + bv[nt];
        }
        __syncthreads();
        int lrow = tid >> 3;                  // 0..31
        int row = half * 32 + lrow;           // 0..63
        float sum = pp[0][row][0] + pp[1][row][0] + pp[2][row][0] + pp[3][row][0];
        float ssq = pp[0][row][1] + pp[1][row][1] + pp[2][row][1] + pp[3][row][1];
        float mean = sum * (1.f / 256.f);
        float var = ssq * (1.f / 256.f) - mean * mean;
        float rstd = rsqrtf(fmaxf(var, 0.f) + 1e-5f);
        long grow = (long)(bm * 64 + row) * 256;
        int c0 = (tid & 7) * 32;
#pragma unroll
        for (int kk = 0; kk < 32; kk += 4) {
            float4 t = *(const float4*)(Tf + lrow * 268 + c0 + kk);
            float4 xv = *(const float4*)(xm + grow + c0 + kk);
            float4 o;
            o.x = (t.x - mean) * rstd * rd(g, goff + c0 + kk + 0, f) + rd(bb, b2off + c0 + kk + 0, f) + xv.x;
            o.y = (t.y - mean) * rstd * rd(g, goff + c0 + kk + 1, f) + rd(bb, b2off + c0 + kk + 1, f) + xv.y;
            o.z = (t.z - mean) * rstd * rd(g, goff + c0 + kk + 2, f) + rd(bb, b2off + c0 + kk + 2, f) + xv.z;
            o.w = (t.w - mean) * rstd * rd(g, goff + c0 + kk + 3, f) + rd(bb, b2off + c0 + kk + 3, f) + xv.w;
            *(float4*)(xm + grow + c0 + kk) = o;
            ushort4 hb; hb.x = f2b(o.x); hb.y = f2b(o.y); hb.z = f2b(o.z); hb.w = f2b(o.w);
            *(ushort4*)(xb + grow + c0 + kk) = hb;
        }
    }
}

// ---------- MFMA window attention: one wave per (head, window, batch) ----------
__global__ __launch_bounds__(256) void k_attn(const unsigned short* __restrict__ qkv, // (NB,56,56,768) bf16
                                              const float* __restrict__ cpb,          // [8][2401] this layer
                                              const void* __restrict__ tau, long toff,
                                              unsigned short* __restrict__ out,       // (NB,56,56,256) un-rolled
                                              int shifted,
                                              const int* __restrict__ flagp) {
    __shared__ __align__(16) unsigned short Pbuf[4][64 * 72];  // P, A-layout staging
    __shared__ __align__(16) unsigned short Vt[4][32 * 72];    // V^T, B-layout staging
    __shared__ float inq_s[4][64], ink_s[4][64];

    const int f = *flagp;
    const int tid = threadIdx.x;
    const int wv = tid >> 6;
    const int lane = tid & 63;
    const int h = blockIdx.x * 4 + wv;
    const int w = blockIdx.y, b = blockIdx.z;
    const int wy = w >> 3, wx = w & 7;
    const int q = lane >> 4;      // quad
    const int c = lane & 15;      // tile row (A/B frag) / tile col (C frag)

    // ---- load Q/K fragments from global + accumulate row square-sums ----
    short8 qa[4], kb[4];
    float sqv[4], skv[4];
#pragma unroll
    for (int mt = 0; mt < 4; mt++) {
        int i = mt * 16 + c; if (i > 48) i = 48;
        int py = i / 7, px = i - py * 7;
        long base = (((long)b * 56 + wy * 7 + py) * 56 + wx * 7 + px) * 768 + h * 32 + q * 8;
        qa[mt] = *(const short8*)(qkv + base);
        kb[mt] = *(const short8*)(qkv + base + 256);
        float sq = 0.f, sk = 0.f;
#pragma unroll
        for (int e = 0; e < 8; e++) {
            float a = b2f((unsigned short)qa[mt][e]); sq += a * a;
            float k2 = b2f((unsigned short)kb[mt][e]); sk += k2 * k2;
        }
        sqv[mt] = sq; skv[mt] = sk;
    }
#pragma unroll
    for (int mt = 0; mt < 4; mt++) {
        float sq = sqv[mt]; sq += __shfl_xor(sq, 16); sq += __shfl_xor(sq, 32);
        float sk = skv[mt]; sk += __shfl_xor(sk, 16); sk += __shfl_xor(sk, 32);
        if (q == 0) {
            inq_s[wv][mt * 16 + c] = 1.f / fmaxf(sqrtf(sq), 1e-12f);
            ink_s[wv][mt * 16 + c] = 1.f / fmaxf(sqrtf(sk), 1e-12f);
        }
    }

    // ---- S = Q K^T (64x64 padded) ----
    floatx4 acc[4][4] = {};
#pragma unroll
    for (int mt = 0; mt < 4; mt++)
#pragma unroll
        for (int nt = 0; nt < 4; nt++)
            acc[mt][nt] = __builtin_amdgcn_mfma_f32_16x16x32_bf16(qa[mt], kb[nt], acc[mt][nt], 0, 0, 0);

    // ---- stage V^T into LDS (zero pad cols first) ----
#pragma unroll
    for (int z = lane; z < 576; z += 64)
        *(uint2*)(&Vt[wv][z * 4]) = make_uint2(0u, 0u);
    if (lane < 49) {
        int py = lane / 7, px = lane - py * 7;
        long base = (((long)b * 56 + wy * 7 + py) * 56 + wx * 7 + px) * 768 + h * 32 + 512;
#pragma unroll
        for (int dd = 0; dd < 32; dd += 8) {
            ushort4 v0 = *(const ushort4*)(qkv + base + dd);
            ushort4 v1 = *(const ushort4*)(qkv + base + dd + 4);
            Vt[wv][(dd + 0) * 72 + lane] = v0.x;
            Vt[wv][(dd + 1) * 72 + lane] = v0.y;
            Vt[wv][(dd + 2) * 72 + lane] = v0.z;
            Vt[wv][(dd + 3) * 72 + lane] = v0.w;
            Vt[wv][(dd + 4) * 72 + lane] = v1.x;
            Vt[wv][(dd + 5) * 72 + lane] = v1.y;
            Vt[wv][(dd + 6) * 72 + lane] = v1.z;
            Vt[wv][(dd + 7) * 72 + lane] = v1.w;
        }
    }

    // ---- scale + cpb + mask + softmax (registers + 16-lane shuffles) -> P in LDS ----
    float scale = 1.f / fmaxf(rd(tau, toff + h, f), 0.01f);
#pragma unroll
    for (int mt = 0; mt < 4; mt++) {
#pragma unroll
        for (int r = 0; r < 4; r++) {
            int i = mt * 16 + q * 4 + r;
            int ci = (i < 49) ? i : 48;
            int pyi = ci / 7, pxi = ci - pyi * 7;
            float qi = inq_s[wv][ci] * scale;
            float vals[4];
#pragma unroll
            for (int nt = 0; nt < 4; nt++) {
                int j = nt * 16 + c;
                if (j < 49) {
                    float v = acc[mt][nt][r] * qi * ink_s[wv][j]
                            + cpb[h * 2401 + ci * 49 + j];
                    if (shifted) {
                        int pyj = j / 7, pxj = j - pyj * 7;
                        if (wy == 7 && ((pyi >= 4) != (pyj >= 4))) v = -1e30f;
                        if (wx == 7 && ((pxi >= 4) != (pxj >= 4))) v = -1e30f;
                    }
                    vals[nt] = v;
                } else vals[nt] = -1e30f;
            }
            float m = fmaxf(fmaxf(vals[0], vals[1]), fmaxf(vals[2], vals[3]));
            m = fmaxf(m, __shfl_xor(m, 1)); m = fmaxf(m, __shfl_xor(m, 2));
            m = fmaxf(m, __shfl_xor(m, 4)); m = fmaxf(m, __shfl_xor(m, 8));
            float s = 0.f;
#pragma unroll
            for (int nt = 0; nt < 4; nt++) { vals[nt] = __expf(vals[nt] - m); s += vals[nt]; }
            s += __shfl_xor(s, 1); s += __shfl_xor(s, 2);
            s += __shfl_xor(s, 4); s += __shfl_xor(s, 8);
            float rinv = 1.f / s;
#pragma unroll
            for (int nt = 0; nt < 4; nt++)
                Pbuf[wv][i * 72 + nt * 16 + c] = f2b(vals[nt] * rinv);
        }
    }

    // ---- O = P V  (64x32, K=64 in 2 steps) ----
    floatx4 accO[4][2] = {};
#pragma unroll
    for (int ks = 0; ks < 2; ks++) {
        short8 pa[4], vb[2];
#pragma unroll
        for (int mt = 0; mt < 4; mt++)
            pa[mt] = *(const short8*)(&Pbuf[wv][(mt * 16 + c) * 72 + ks * 32 + q * 8]);
#pragma unroll
        for (int nt = 0; nt < 2; nt++)
            vb[nt] = *(const short8*)(&Vt[wv][(nt * 16 + c) * 72 + ks * 32 + q * 8]);
#pragma unroll
        for (int mt = 0; mt < 4; mt++)
#pragma unroll
            for (int nt = 0; nt < 2; nt++)
                accO[mt][nt] = __builtin_amdgcn_mfma_f32_16x16x32_bf16(pa[mt], vb[nt], accO[mt][nt], 0, 0, 0);
    }

    // ---- write O (un-roll fold) ----
    int sh = shifted ? 3 : 0;
#pragma unroll
    for (int mt = 0; mt < 4; mt++) {
#pragma unroll
        for (int r = 0; r < 4; r++) {
            int i = mt * 16 + q * 4 + r;
            if (i < 49) {
                int py = i / 7, px = i - py * 7;
                int yo = wy * 7 + py + sh; if (yo >= 56) yo -= 56;
                int xo = wx * 7 + px + sh; if (xo >= 56) xo -= 56;
                long ob = (((long)b * 56 + yo) * 56 + xo) * 256 + h * 32;
                out[ob + c]      = f2b(accO[mt][0][r]);
                out[ob + 16 + c] = f2b(accO[mt][1][r]);
            }
        }
    }
}

// ---------- final LN -> out (dtype per flag) ----------
__global__ __launch_bounds__(256) void k_final(const float* __restrict__ xm,
                                               const void* __restrict__ g,
                                               const void* __restrict__ bb,
                                               void* __restrict__ out,
                                               const int* __restrict__ flagp) {
    const int f = *flagp;
    int t = blockIdx.x, c = threadIdx.x;
    long off = (long)t * 256 + c;
    float v = xm[off];
    __shared__ float red[256];
    red[c] = v; __syncthreads();
#pragma unroll
    for (int s = 128; s > 0; s >>= 1) {
        if (c < s) red[c] += red[c + s];
        __syncthreads();
    }
    float mean = red[0] * (1.f / 256.f);
    __syncthreads();
    float d = v - mean;
    red[c] = d * d; __syncthreads();
#pragma unroll
    for (int s = 128; s > 0; s >>= 1) {
        if (c < s) red[c] += red[c + s];
        __syncthreads();
    }
    float var = red[0] * (1.f / 256.f);
    float ln = d * rsqrtf(var + 1e-5f) * rd(g, c, f) + rd(bb, c, f);
    if (f) ((float*)out)[off] = ln;
    else   ((unsigned short*)out)[off] = f2b(ln);
}

// ---------- launch ----------
extern "C" void kernel_launch(void* const* d_in, const int* in_sizes, int n_in,
                              void* d_out, int out_size, void* d_ws, size_t ws_size,
                              hipStream_t stream) {
    char* ws = (char*)d_ws;
    // fixed region
    float*          xm    = (float*)(ws + 0);                    // 51,380,224 B
    unsigned short* wt    = (unsigned short*)(ws + 51380224);    //  3,145,728 B
    float*          cpb   = (float*)(ws + 54525952);             //    153,664 B
    int*            flagp = (int*)(ws + 54679616);
    const size_t DYN = 54680576;

    // adaptive group count: batches are independent; pick largest Mg that fits ws
    long Mg = NTOK_; int G = 1;
    while (G <= 8) {
        Mg = NTOK_ / G;
        if (DYN + (size_t)Mg * 2560 <= ws_size) break;
        G <<= 1;
    }
    if (G > 8) { G = 8; Mg = NTOK_ / 8; }
    const int NB = 16 / G;

    unsigned short* xb   = (unsigned short*)(ws + DYN);               // Mg*512 B
    unsigned short* qkvb = (unsigned short*)(ws + DYN + Mg * 512);    // Mg*1536 B
    unsigned short* hid  = (unsigned short*)(ws + DYN + Mg * 512);    // Mg*2048 B (alias qkvb)

    k_detect<<<1, 256, 0, stream>>>((const unsigned short*)d_in[0], flagp);

    for (int l = 0; l < 2; l++) {
        unsigned short* base = wt + (long)l * 786432;
        k_transpose<<<dim3(768), 256, 0, stream>>>(d_in[2],  (long)l * 196608, base,          256, 768,  flagp);
        k_transpose<<<dim3(256), 256, 0, stream>>>(d_in[8],  (long)l * 65536,  base + 196608, 256, 256,  flagp);
        k_transpose<<<dim3(1024), 256, 0, stream>>>(d_in[12], (long)l * 262144, base + 262144, 256, 1024, flagp);
        k_transpose<<<dim3(1024), 256, 0, stream>>>(d_in[14], (long)l * 262144, base + 524288, 1024, 256, flagp);
    }
    k_cpb<<<dim3(2401, 2), 512, 0, stream>>>(d_in[4], d_in[5], d_in[6], d_in[7], cpb, flagp);
    k_add_spe<<<dim3(12544), 256, 0, stream>>>(d_in[0], d_in[1], xm, flagp);

    for (int l = 0; l < 2; l++) {
        int sh = (l & 1) ? 3 : 0;
        unsigned short* base = wt + (long)l * 786432;
        for (int g = 0; g < G; g++) {
            long m0 = (long)g * Mg;
            k_cast_roll<<<dim3(Mg / 4), 256, 0, stream>>>(xm + m0 * 256, xb, sh);
            // qkv = xb @ qkv_w -> bf16
            gemm_bt<<<dim3(Mg / 128, 6), 256, 0, stream>>>(xb, base, nullptr, 0, qkvb,
                                                           (int)Mg, 768, 256, 4, flagp);
            k_attn<<<dim3(2, 64, NB), 256, 0, stream>>>(qkvb, cpb + (long)l * 19208,
                                                        d_in[3], (long)l * 8, xb, (l & 1), flagp);
            // proj + LN1 + residual (fused)
            gemm_ln<<<dim3(Mg / 64), 256, 0, stream>>>(xb, base + 196608, d_in[9], (long)l * 256,
                                                       d_in[10], (long)l * 256, d_in[11], (long)l * 256,
                                                       xm + m0 * 256, xb, 256, flagp);
            // hidden = gelu(xb @ fw1 + fb1) -> bf16
            gemm_bt<<<dim3(Mg / 128, 8), 256, 0, stream>>>(xb, base + 262144, d_in[13], (long)l * 1024,
                                                           hid, (int)Mg, 1024, 256, 1 | 2 | 4, flagp);
            // fw2 + LN2 + residual (fused)
            gemm_ln<<<dim3(Mg / 64), 256, 0, stream>>>(hid, base + 524288, d_in[15], (long)l * 256,
                                                       d_in[16], (long)l * 256, d_in[17], (long)l * 256,
                                                       xm + m0 * 256, xb, 1024, flagp);
        }
    }
    k_final<<<dim3(NTOK_), 256, 0, stream>>>(xm, d_in[18], d_in[19], d_out, flagp);
}

// Round 6
// 956.833 us; speedup vs baseline: 1.2578x; 1.2578x over previous
//
#include <hip/hip_runtime.h>
#include <hip/hip_bf16.h>
#include <math.h>

// ---------- types / helpers ----------
typedef short    short8  __attribute__((ext_vector_type(8)));
typedef float    floatx4 __attribute__((ext_vector_type(4)));

__device__ __forceinline__ float b2f(unsigned short u) {
    union { float f; unsigned int i; } v; v.i = ((unsigned int)u) << 16; return v.f;
}
__device__ __forceinline__ unsigned short f2b(float f) {
    union { float f; unsigned int i; } v; v.f = f;
    unsigned int b = v.i;
    return (unsigned short)((b + 0x7FFFu + ((b >> 16) & 1u)) >> 16);
}
// dual-dtype read: element i of input tensor that is bf16 (flag=0) or f32 (flag=1)
__device__ __forceinline__ float rd(const void* p, long i, int f) {
    return f ? ((const float*)p)[i] : b2f(((const unsigned short*)p)[i]);
}
// fast GELU (tanh form, |err|<~3e-3)
__device__ __forceinline__ float fgelu(float x) {
    float u = 0.7978845608f * x * (1.f + 0.044715f * x * x);
    float e = __expf(-2.f * fabsf(u));
    float th = 1.f - 2.f * e / (1.f + e);
    th = (u < 0.f) ? -th : th;
    return 0.5f * x * (1.f + th);
}

#define NTOK_ 50176   // 16*56*56

// ---------- dtype detector: bf16 N(0,1) never has exp>=0x90; f32 misread does ----------
__global__ __launch_bounds__(256) void k_detect(const unsigned short* __restrict__ x,
                                                int* __restrict__ flag) {
    __shared__ int cnt;
    if (threadIdx.x == 0) cnt = 0;
    __syncthreads();
    unsigned short v = x[threadIdx.x];
    int e = (v >> 7) & 0xFF;
    if (e >= 0x90) atomicAdd(&cnt, 1);
    __syncthreads();
    if (threadIdx.x == 0) *flag = (cnt >= 8) ? 1 : 0;
}

// ---------- xm = x + spe -> fp32 ----------
__global__ __launch_bounds__(256) void k_add_spe(const void* __restrict__ x,
                                                 const void* __restrict__ spe,
                                                 float* __restrict__ xm,
                                                 const int* __restrict__ flagp) {
    const int f = *flagp;
    long i = ((long)blockIdx.x * 256 + threadIdx.x) * 4;
    float4 o;
    if (f) {
        float4 a = *(const float4*)((const float*)x + i);
        float4 b = *(const float4*)((const float*)spe + i);
        o.x = a.x + b.x; o.y = a.y + b.y; o.z = a.z + b.z; o.w = a.w + b.w;
    } else {
        ushort4 a = *(const ushort4*)((const unsigned short*)x + i);
        ushort4 b = *(const ushort4*)((const unsigned short*)spe + i);
        o.x = b2f(a.x) + b2f(b.x); o.y = b2f(a.y) + b2f(b.y);
        o.z = b2f(a.z) + b2f(b.z); o.w = b2f(a.w) + b2f(b.w);
    }
    *(float4*)(xm + i) = o;
}

// ---------- weight transpose: (K,N) -> (N,K) bf16 ----------
__global__ __launch_bounds__(256) void k_transpose(const void* __restrict__ in, long ioff,
                                                   unsigned short* __restrict__ out,
                                                   int K, int N,
                                                   const int* __restrict__ flagp) {
    const int f = *flagp;
    int i = blockIdx.x * 256 + threadIdx.x;
    if (i >= K * N) return;
    int k = i / N, n = i - k * N;
    unsigned short o;
    if (f) o = f2b(((const float*)in)[ioff + i]);
    else   o = ((const unsigned short*)in)[ioff + i];   // bit-exact passthrough
    out[(long)n * K + k] = o;
}

// ---------- CPB table: relu(REL@cw1+cb1)@cw2+cb2 -> cpb[l][head][2401] ----------
__global__ __launch_bounds__(512) void k_cpb(const void* __restrict__ cw1,
                                             const void* __restrict__ cb1,
                                             const void* __restrict__ cw2,
                                             const void* __restrict__ cb2,
                                             float* __restrict__ cpb,
                                             const int* __restrict__ flagp) {
    const int f = *flagp;
    int p = blockIdx.x;      // pair index i*49+j
    int l = blockIdx.y;      // layer
    int t = threadIdx.x;     // 0..511
    int i = p / 49, j = p - i * 49;
    int yi = i / 7, xi = i - yi * 7, yj = j / 7, xj = j - yj * 7;
    float dy = (float)(yj - yi), dx = (float)(xj - xi);
    float sy = (dy > 0.f) ? 1.f : ((dy < 0.f) ? -1.f : 0.f);
    float sx = (dx > 0.f) ? 1.f : ((dx < 0.f) ? -1.f : 0.f);
    float r0 = sy * log1pf(fabsf(dy));
    float r1 = sx * log1pf(fabsf(dx));
    float h = r0 * rd(cw1, l * 1024 + t, f) + r1 * rd(cw1, l * 1024 + 512 + t, f)
            + rd(cb1, l * 512 + t, f);
    h = fmaxf(h, 0.f);
    __shared__ float red[512];
    for (int hh = 0; hh < 8; hh++) {
        red[t] = h * rd(cw2, (long)(l * 512 + t) * 8 + hh, f);
        __syncthreads();
        for (int s = 256; s > 0; s >>= 1) {
            if (t < s) red[t] += red[t + s];
            __syncthreads();
        }
        if (t == 0) cpb[((long)l * 8 + hh) * 2401 + p] = red[0] + rd(cb2, l * 8 + hh, f);
        __syncthreads();
    }
}

// ---------- cast (+roll) fp32 xm(group) -> bf16 xb(group) ----------
__global__ __launch_bounds__(256) void k_cast_roll(const float* __restrict__ xmg,
                                                   unsigned short* __restrict__ xb, int shift) {
    int gid = blockIdx.x * 256 + threadIdx.x;       // Mg*64 threads
    int c4 = (gid & 63) * 4;
    int t = gid >> 6;
    int x = t % 56; int t2 = t / 56;
    int y = t2 % 56;
    int b = t2 / 56;                                 // local batch in group
    int ys = y + shift; if (ys >= 56) ys -= 56;
    int xs = x + shift; if (xs >= 56) xs -= 56;
    float4 v = *(const float4*)(xmg + (((long)b * 3136 + ys * 56 + xs) * 256 + c4));
    ushort4 o; o.x = f2b(v.x); o.y = f2b(v.y); o.z = f2b(v.z); o.w = f2b(v.w);
    *(ushort4*)(xb + ((long)t * 256 + c4)) = o;
}

// ---------- MFMA GEMM: C[M,N] = A[M,K] @ Bt[N,K]^T (+bias)(+gelu) ----------
// flags: 1=bias, 2=gelu, 4=store bf16 (else fp32)
__global__ __launch_bounds__(256) void gemm_bt(const unsigned short* __restrict__ A,
                                               const unsigned short* __restrict__ Bt,
                                               const void* __restrict__ bias, long boff,
                                               void* __restrict__ Cp,
                                               int M, int N, int K, int flags,
                                               const int* __restrict__ flagp) {
    __shared__ __align__(16) unsigned short smem[16896];
    unsigned short* As = smem;            // 128 x 40
    unsigned short* Bs = smem + 5120;     // 128 x 40
    const int f = *flagp;
    const int tid = threadIdx.x;
    const int lane = tid & 63;
    const int wave = tid >> 6;
    const int wrow = (wave >> 1) * 64;
    const int wcol = (wave & 1) * 64;
    const int bm = blockIdx.x, bn = blockIdx.y;

    floatx4 acc[4][4] = {};

    const int arow = tid >> 2;       // 0..63
    const int aseg = (tid & 3) * 8;  // 0,8,16,24
    const unsigned short* Ag = A + (long)(bm * 128 + arow) * K + aseg;
    const unsigned short* Bg = Bt + (long)(bn * 128 + arow) * K + aseg;
    const long arow2 = (long)64 * K;

    const int q = lane >> 4;        // quad 0..3
    const int mrow = lane & 15;

    for (int k0 = 0; k0 < K; k0 += 32) {
        uint4 a0 = *(const uint4*)(Ag + k0);
        uint4 a1 = *(const uint4*)(Ag + k0 + arow2);
        uint4 b0 = *(const uint4*)(Bg + k0);
        uint4 b1 = *(const uint4*)(Bg + k0 + arow2);
        __syncthreads();
        *(uint4*)(As + arow * 40 + aseg) = a0;
        *(uint4*)(As + (arow + 64) * 40 + aseg) = a1;
        *(uint4*)(Bs + arow * 40 + aseg) = b0;
        *(uint4*)(Bs + (arow + 64) * 40 + aseg) = b1;
        __syncthreads();

        short8 af_[4], bf_[4];
#pragma unroll
        for (int mt = 0; mt < 4; mt++)
            af_[mt] = *(const short8*)(As + (wrow + mt * 16 + mrow) * 40 + q * 8);
#pragma unroll
        for (int nt = 0; nt < 4; nt++)
            bf_[nt] = *(const short8*)(Bs + (wcol + nt * 16 + mrow) * 40 + q * 8);
#pragma unroll
        for (int mt = 0; mt < 4; mt++)
#pragma unroll
            for (int nt = 0; nt < 4; nt++)
                acc[mt][nt] = __builtin_amdgcn_mfma_f32_16x16x32_bf16(af_[mt], bf_[nt], acc[mt][nt], 0, 0, 0);
    }

    __syncthreads();   // K-loop LDS reads complete before epilogue reuse

    if (flags & 4) {
        // ---- bf16 output: stage full 128x128 tile (row pad -> 132) ----
        unsigned short* T = smem;
#pragma unroll
        for (int nt = 0; nt < 4; nt++) {
            int col = wcol + nt * 16 + mrow;
            float bv = (flags & 1) ? rd(bias, boff + bn * 128 + col, f) : 0.f;
#pragma unroll
            for (int mt = 0; mt < 4; mt++) {
                int row0 = wrow + mt * 16 + q * 4;
#pragma unroll
                for (int r = 0; r < 4; r++) {
                    float v = acc[mt][nt][r] + bv;
                    if (flags & 2) v = fgelu(v);
                    T[(row0 + r) * 132 + col] = f2b(v);
                }
            }
        }
        __syncthreads();
        unsigned short* Cu = (unsigned short*)Cp;
        int row = tid >> 4;              // 0..15
        int col8 = (tid & 15) * 8;
#pragma unroll
        for (int p = 0; p < 8; p++) {
            int rr = p * 16 + row;
            *(uint4*)(Cu + (long)(bm * 128 + rr) * N + bn * 128 + col8) =
                *(const uint4*)(T + rr * 132 + col8);
        }
    } else {
        // ---- fp32 output: two 64-row halves through LDS ----
        float* Tf = (float*)smem;        // 64 x 132 floats
        float* Cf = (float*)Cp;
        float bvc[4];
#pragma unroll
        for (int nt = 0; nt < 4; nt++)
            bvc[nt] = (flags & 1) ? rd(bias, boff + bn * 128 + wcol + nt * 16 + mrow, f) : 0.f;
        int row = tid >> 5;              // 0..7
        int col4 = (tid & 31) * 4;
#pragma unroll
        for (int half = 0; half < 2; half++) {
            if (half) __syncthreads();
            if (wrow == half * 64) {
#pragma unroll
                for (int nt = 0; nt < 4; nt++) {
                    int col = wcol + nt * 16 + mrow;
#pragma unroll
                    for (int mt = 0; mt < 4; mt++) {
                        int lrow0 = mt * 16 + q * 4;
#pragma unroll
                        for (int r = 0; r < 4; r++) {
                            float v = acc[mt][nt][r] + bvc[nt];
                            if (flags & 2) v = fgelu(v);
                            Tf[(lrow0 + r) * 132 + col] = v;
                        }
                    }
                }
            }
            __syncthreads();
#pragma unroll
            for (int p = 0; p < 8; p++) {
                int rr = p * 8 + row;
                *(float4*)(Cf + (long)(bm * 128 + half * 64 + rr) * N + bn * 128 + col4) =
                    *(const float4*)(Tf + rr * 132 + col4);
            }
        }
    }
}

// ---------- fused GEMM(N=256) + PostNorm-LN + residual ----------
// t = A[64 rows, K] @ Bt[256,K]^T + bias; xm += LN(t)*g+bb; xb = bf16(xm).
// LN apply: one WAVE per row (lane i owns cols 4i..4i+3) so every xm/xb store
// instruction is contiguous (round-5: per-thread 32-col slices caused 3.8x
// HBM write amplification, 292 MB vs 77 MB ideal).
__global__ __launch_bounds__(256) void gemm_ln(const unsigned short* __restrict__ A,
                                               const unsigned short* __restrict__ Bt,
                                               const void* __restrict__ bias, long boff,
                                               const void* __restrict__ g, long goff,
                                               const void* __restrict__ bb, long b2off,
                                               float* __restrict__ xm,
                                               unsigned short* __restrict__ xb,
                                               int K,
                                               const int* __restrict__ flagp) {
    __shared__ __align__(16) unsigned short smem[17152];   // 34304 B (staging / Tf)
    __shared__ float pp[4][64][2];
    unsigned short* As = smem;            // 64 x 40
    unsigned short* Bs = smem + 2560;     // 256 x 40
    const int f = *flagp;
    const int tid = threadIdx.x;
    const int lane = tid & 63;
    const int wv = tid >> 6;
    const int wcol = wv * 64;
    const int bm = blockIdx.x;

    floatx4 acc[4][4] = {};
    const int arow = tid >> 2;       // 0..63
    const int aseg = (tid & 3) * 8;
    const unsigned short* Ag = A + (long)(bm * 64 + arow) * K + aseg;
    const unsigned short* Bg = Bt + (long)arow * K + aseg;
    const long brow2 = (long)64 * K;
    const int q = lane >> 4;
    const int c = lane & 15;

    for (int k0 = 0; k0 < K; k0 += 32) {
        uint4 a0 = *(const uint4*)(Ag + k0);
        uint4 b0 = *(const uint4*)(Bg + k0);
        uint4 b1 = *(const uint4*)(Bg + k0 + brow2);
        uint4 b2 = *(const uint4*)(Bg + k0 + 2 * brow2);
        uint4 b3 = *(const uint4*)(Bg + k0 + 3 * brow2);
        __syncthreads();
        *(uint4*)(As + arow * 40 + aseg) = a0;
        *(uint4*)(Bs + arow * 40 + aseg) = b0;
        *(uint4*)(Bs + (arow + 64) * 40 + aseg) = b1;
        *(uint4*)(Bs + (arow + 128) * 40 + aseg) = b2;
        *(uint4*)(Bs + (arow + 192) * 40 + aseg) = b3;
        __syncthreads();

        short8 af_[4], bf_[4];
#pragma unroll
        for (int mt = 0; mt < 4; mt++)
            af_[mt] = *(const short8*)(As + (mt * 16 + c) * 40 + q * 8);
#pragma unroll
        for (int nt = 0; nt < 4; nt++)
            bf_[nt] = *(const short8*)(Bs + (wcol + nt * 16 + c) * 40 + q * 8);
#pragma unroll
        for (int mt = 0; mt < 4; mt++)
#pragma unroll
            for (int nt = 0; nt < 4; nt++)
                acc[mt][nt] = __builtin_amdgcn_mfma_f32_16x16x32_bf16(af_[mt], bf_[nt], acc[mt][nt], 0, 0, 0);
    }
    __syncthreads();

    // ---- per-row sum / sumsq (bias included), cross-wave via LDS ----
    float bv[4];
#pragma unroll
    for (int nt = 0; nt < 4; nt++)
        bv[nt] = rd(bias, boff + wcol + nt * 16 + c, f);
#pragma unroll
    for (int mt = 0; mt < 4; mt++) {
#pragma unroll
        for (int r = 0; r < 4; r++) {
            float s1 = 0.f, s2 = 0.f;
#pragma unroll
            for (int nt = 0; nt < 4; nt++) {
                float v = acc[mt][nt][r] + bv[nt];
                s1 += v; s2 += v * v;
            }
            s1 += __shfl_xor(s1, 1); s2 += __shfl_xor(s2, 1);
            s1 += __shfl_xor(s1, 2); s2 += __shfl_xor(s2, 2);
            s1 += __shfl_xor(s1, 4); s2 += __shfl_xor(s2, 4);
            s1 += __shfl_xor(s1, 8); s2 += __shfl_xor(s2, 8);
            if (c == 0) {
                pp[wv][mt * 16 + q * 4 + r][0] = s1;
                pp[wv][mt * 16 + q * 4 + r][1] = s2;
            }
        }
    }

    // ---- preload LN params for this lane's 4 columns (once per block) ----
    const int c0 = lane * 4;
    float4 gv, bbv;
    gv.x = rd(g, goff + c0 + 0, f); gv.y = rd(g, goff + c0 + 1, f);
    gv.z = rd(g, goff + c0 + 2, f); gv.w = rd(g, goff + c0 + 3, f);
    bbv.x = rd(bb, b2off + c0 + 0, f); bbv.y = rd(bb, b2off + c0 + 1, f);
    bbv.z = rd(bb, b2off + c0 + 2, f); bbv.w = rd(bb, b2off + c0 + 3, f);
    __syncthreads();

    // ---- restage fp32 (stride 268) + wave-per-row coalesced LN apply ----
    float* Tf = (float*)smem;      // 32 x 268 fp32
#pragma unroll
    for (int half = 0; half < 2; half++) {
        if (half) __syncthreads();
#pragma unroll
        for (int mt2 = 0; mt2 < 2; mt2++) {
            int mt = half * 2 + mt2;
#pragma unroll
            for (int nt = 0; nt < 4; nt++)
#pragma unroll
                for (int r = 0; r < 4; r++)
                    Tf[(mt2 * 16 + q * 4 + r) * 268 + wcol + nt * 16 + c] = acc[mt][nt][r] + bv[nt];
        }
        __syncthreads();
#pragma unroll
        for (int it = 0; it < 8; it++) {
            int lr = wv * 8 + it;            // row within half, this wave
            int row = half * 32 + lr;
            float sum = pp[0][row][0] + pp[1][row][0] + pp[2][row][0] + pp[3][row][0];
            float ssq = pp[0][row][1] + pp[1][row][1] + pp[2][row][1] + pp[3][row][1];
            float mean = sum * (1.f / 256.f);
            float var = ssq * (1.f / 256.f) - mean * mean;
            float rstd = rsqrtf(fmaxf(var, 0.f) + 1e-5f);
            long grow = (long)(bm * 64 + row) * 256;
            float4 t = *(const float4*)(Tf + lr * 268 + c0);
            float4 xv = *(const float4*)(xm + grow + c0);
            float4 o;
            o.x = (t.x - mean) * rstd * gv.x + bbv.x + xv.x;
            o.y = (t.y - mean) * rstd * gv.y + bbv.y + xv.y;
            o.z = (t.z - mean) * rstd * gv.z + bbv.z + xv.z;
            o.w = (t.w - mean) * rstd * gv.w + bbv.w + xv.w;
            *(float4*)(xm + grow + c0) = o;
            ushort4 hb; hb.x = f2b(o.x); hb.y = f2b(o.y); hb.z = f2b(o.z); hb.w = f2b(o.w);
            *(ushort4*)(xb + grow + c0) = hb;
        }
    }
}

// ---------- MFMA window attention: one wave per (head, window, batch) ----------
__global__ __launch_bounds__(256) void k_attn(const unsigned short* __restrict__ qkv, // (NB,56,56,768) bf16
                                              const float* __restrict__ cpb,          // [8][2401] this layer
                                              const void* __restrict__ tau, long toff,
                                              unsigned short* __restrict__ out,       // (NB,56,56,256) un-rolled
                                              int shifted,
                                              const int* __restrict__ flagp) {
    __shared__ __align__(16) unsigned short Pbuf[4][64 * 72];  // P, A-layout staging
    __shared__ __align__(16) unsigned short Vt[4][32 * 72];    // V^T, B-layout staging
    __shared__ float inq_s[4][64], ink_s[4][64];

    const int f = *flagp;
    const int tid = threadIdx.x;
    const int wv = tid >> 6;
    const int lane = tid & 63;
    const int h = blockIdx.x * 4 + wv;
    const int w = blockIdx.y, b = blockIdx.z;
    const int wy = w >> 3, wx = w & 7;
    const int q = lane >> 4;      // quad
    const int c = lane & 15;      // tile row (A/B frag) / tile col (C frag)

    // ---- load Q/K fragments from global + accumulate row square-sums ----
    short8 qa[4], kb[4];
    float sqv[4], skv[4];
#pragma unroll
    for (int mt = 0; mt < 4; mt++) {
        int i = mt * 16 + c; if (i > 48) i = 48;
        int py = i / 7, px = i - py * 7;
        long base = (((long)b * 56 + wy * 7 + py) * 56 + wx * 7 + px) * 768 + h * 32 + q * 8;
        qa[mt] = *(const short8*)(qkv + base);
        kb[mt] = *(const short8*)(qkv + base + 256);
        float sq = 0.f, sk = 0.f;
#pragma unroll
        for (int e = 0; e < 8; e++) {
            float a = b2f((unsigned short)qa[mt][e]); sq += a * a;
            float k2 = b2f((unsigned short)kb[mt][e]); sk += k2 * k2;
        }
        sqv[mt] = sq; skv[mt] = sk;
    }
#pragma unroll
    for (int mt = 0; mt < 4; mt++) {
        float sq = sqv[mt]; sq += __shfl_xor(sq, 16); sq += __shfl_xor(sq, 32);
        float sk = skv[mt]; sk += __shfl_xor(sk, 16); sk += __shfl_xor(sk, 32);
        if (q == 0) {
            inq_s[wv][mt * 16 + c] = 1.f / fmaxf(sqrtf(sq), 1e-12f);
            ink_s[wv][mt * 16 + c] = 1.f / fmaxf(sqrtf(sk), 1e-12f);
        }
    }

    // ---- S = Q K^T (64x64 padded) ----
    floatx4 acc[4][4] = {};
#pragma unroll
    for (int mt = 0; mt < 4; mt++)
#pragma unroll
        for (int nt = 0; nt < 4; nt++)
            acc[mt][nt] = __builtin_amdgcn_mfma_f32_16x16x32_bf16(qa[mt], kb[nt], acc[mt][nt], 0, 0, 0);

    // ---- stage V^T into LDS (zero pad cols first) ----
#pragma unroll
    for (int z = lane; z < 576; z += 64)
        *(uint2*)(&Vt[wv][z * 4]) = make_uint2(0u, 0u);
    if (lane < 49) {
        int py = lane / 7, px = lane - py * 7;
        long base = (((long)b * 56 + wy * 7 + py) * 56 + wx * 7 + px) * 768 + h * 32 + 512;
#pragma unroll
        for (int dd = 0; dd < 32; dd += 8) {
            ushort4 v0 = *(const ushort4*)(qkv + base + dd);
            ushort4 v1 = *(const ushort4*)(qkv + base + dd + 4);
            Vt[wv][(dd + 0) * 72 + lane] = v0.x;
            Vt[wv][(dd + 1) * 72 + lane] = v0.y;
            Vt[wv][(dd + 2) * 72 + lane] = v0.z;
            Vt[wv][(dd + 3) * 72 + lane] = v0.w;
            Vt[wv][(dd + 4) * 72 + lane] = v1.x;
            Vt[wv][(dd + 5) * 72 + lane] = v1.y;
            Vt[wv][(dd + 6) * 72 + lane] = v1.z;
            Vt[wv][(dd + 7) * 72 + lane] = v1.w;
        }
    }

    // ---- scale + cpb + mask + softmax (registers + 16-lane shuffles) -> P in LDS ----
    float scale = 1.f / fmaxf(rd(tau, toff + h, f), 0.01f);
#pragma unroll
    for (int mt = 0; mt < 4; mt++) {
#pragma unroll
        for (int r = 0; r < 4; r++) {
            int i = mt * 16 + q * 4 + r;
            int ci = (i < 49) ? i : 48;
            int pyi = ci / 7, pxi = ci - pyi * 7;
            float qi = inq_s[wv][ci] * scale;
            float vals[4];
#pragma unroll
            for (int nt = 0; nt < 4; nt++) {
                int j = nt * 16 + c;
                if (j < 49) {
                    float v = acc[mt][nt][r] * qi * ink_s[wv][j]
                            + cpb[h * 2401 + ci * 49 + j];
                    if (shifted) {
                        int pyj = j / 7, pxj = j - pyj * 7;
                        if (wy == 7 && ((pyi >= 4) != (pyj >= 4))) v = -1e30f;
                        if (wx == 7 && ((pxi >= 4) != (pxj >= 4))) v = -1e30f;
                    }
                    vals[nt] = v;
                } else vals[nt] = -1e30f;
            }
            float m = fmaxf(fmaxf(vals[0], vals[1]), fmaxf(vals[2], vals[3]));
            m = fmaxf(m, __shfl_xor(m, 1)); m = fmaxf(m, __shfl_xor(m, 2));
            m = fmaxf(m, __shfl_xor(m, 4)); m = fmaxf(m, __shfl_xor(m, 8));
            float s = 0.f;
#pragma unroll
            for (int nt = 0; nt < 4; nt++) { vals[nt] = __expf(vals[nt] - m); s += vals[nt]; }
            s += __shfl_xor(s, 1); s += __shfl_xor(s, 2);
            s += __shfl_xor(s, 4); s += __shfl_xor(s, 8);
            float rinv = 1.f / s;
#pragma unroll
            for (int nt = 0; nt < 4; nt++)
                Pbuf[wv][i * 72 + nt * 16 + c] = f2b(vals[nt] * rinv);
        }
    }

    // ---- O = P V  (64x32, K=64 in 2 steps) ----
    floatx4 accO[4][2] = {};
#pragma unroll
    for (int ks = 0; ks < 2; ks++) {
        short8 pa[4], vb[2];
#pragma unroll
        for (int mt = 0; mt < 4; mt++)
            pa[mt] = *(const short8*)(&Pbuf[wv][(mt * 16 + c) * 72 + ks * 32 + q * 8]);
#pragma unroll
        for (int nt = 0; nt < 2; nt++)
            vb[nt] = *(const short8*)(&Vt[wv][(nt * 16 + c) * 72 + ks * 32 + q * 8]);
#pragma unroll
        for (int mt = 0; mt < 4; mt++)
#pragma unroll
            for (int nt = 0; nt < 2; nt++)
                accO[mt][nt] = __builtin_amdgcn_mfma_f32_16x16x32_bf16(pa[mt], vb[nt], accO[mt][nt], 0, 0, 0);
    }

    // ---- write O (un-roll fold) ----
    int sh = shifted ? 3 : 0;
#pragma unroll
    for (int mt = 0; mt < 4; mt++) {
#pragma unroll
        for (int r = 0; r < 4; r++) {
            int i = mt * 16 + q * 4 + r;
            if (i < 49) {
                int py = i / 7, px = i - py * 7;
                int yo = wy * 7 + py + sh; if (yo >= 56) yo -= 56;
                int xo = wx * 7 + px + sh; if (xo >= 56) xo -= 56;
                long ob = (((long)b * 56 + yo) * 56 + xo) * 256 + h * 32;
                out[ob + c]      = f2b(accO[mt][0][r]);
                out[ob + 16 + c] = f2b(accO[mt][1][r]);
            }
        }
    }
}

// ---------- final LN -> out (dtype per flag) ----------
__global__ __launch_bounds__(256) void k_final(const float* __restrict__ xm,
                                               const void* __restrict__ g,
                                               const void* __restrict__ bb,
                                               void* __restrict__ out,
                                               const int* __restrict__ flagp) {
    const int f = *flagp;
    int t = blockIdx.x, c = threadIdx.x;
    long off = (long)t * 256 + c;
    float v = xm[off];
    __shared__ float red[256];
    red[c] = v; __syncthreads();
#pragma unroll
    for (int s = 128; s > 0; s >>= 1) {
        if (c < s) red[c] += red[c + s];
        __syncthreads();
    }
    float mean = red[0] * (1.f / 256.f);
    __syncthreads();
    float d = v - mean;
    red[c] = d * d; __syncthreads();
#pragma unroll
    for (int s = 128; s > 0; s >>= 1) {
        if (c < s) red[c] += red[c + s];
        __syncthreads();
    }
    float var = red[0] * (1.f / 256.f);
    float ln = d * rsqrtf(var + 1e-5f) * rd(g, c, f) + rd(bb, c, f);
    if (f) ((float*)out)[off] = ln;
    else   ((unsigned short*)out)[off] = f2b(ln);
}

// ---------- launch ----------
extern "C" void kernel_launch(void* const* d_in, const int* in_sizes, int n_in,
                              void* d_out, int out_size, void* d_ws, size_t ws_size,
                              hipStream_t stream) {
    char* ws = (char*)d_ws;
    // fixed region
    float*          xm    = (float*)(ws + 0);                    // 51,380,224 B
    unsigned short* wt    = (unsigned short*)(ws + 51380224);    //  3,145,728 B
    float*          cpb   = (float*)(ws + 54525952);             //    153,664 B
    int*            flagp = (int*)(ws + 54679616);
    const size_t DYN = 54680576;

    // adaptive group count: batches are independent; pick largest Mg that fits ws
    long Mg = NTOK_; int G = 1;
    while (G <= 8) {
        Mg = NTOK_ / G;
        if (DYN + (size_t)Mg * 2560 <= ws_size) break;
        G <<= 1;
    }
    if (G > 8) { G = 8; Mg = NTOK_ / 8; }
    const int NB = 16 / G;

    unsigned short* xb   = (unsigned short*)(ws + DYN);               // Mg*512 B
    unsigned short* qkvb = (unsigned short*)(ws + DYN + Mg * 512);    // Mg*1536 B
    unsigned short* hid  = (unsigned short*)(ws + DYN + Mg * 512);    // Mg*2048 B (alias qkvb)

    k_detect<<<1, 256, 0, stream>>>((const unsigned short*)d_in[0], flagp);

    for (int l = 0; l < 2; l++) {
        unsigned short* base = wt + (long)l * 786432;
        k_transpose<<<dim3(768), 256, 0, stream>>>(d_in[2],  (long)l * 196608, base,          256, 768,  flagp);
        k_transpose<<<dim3(256), 256, 0, stream>>>(d_in[8],  (long)l * 65536,  base + 196608, 256, 256,  flagp);
        k_transpose<<<dim3(1024), 256, 0, stream>>>(d_in[12], (long)l * 262144, base + 262144, 256, 1024, flagp);
        k_transpose<<<dim3(1024), 256, 0, stream>>>(d_in[14], (long)l * 262144, base + 524288, 1024, 256, flagp);
    }
    k_cpb<<<dim3(2401, 2), 512, 0, stream>>>(d_in[4], d_in[5], d_in[6], d_in[7], cpb, flagp);
    k_add_spe<<<dim3(12544), 256, 0, stream>>>(d_in[0], d_in[1], xm, flagp);

    for (int l = 0; l < 2; l++) {
        int sh = (l & 1) ? 3 : 0;
        unsigned short* base = wt + (long)l * 786432;
        for (int g = 0; g < G; g++) {
            long m0 = (long)g * Mg;
            k_cast_roll<<<dim3(Mg / 4), 256, 0, stream>>>(xm + m0 * 256, xb, sh);
            // qkv = xb @ qkv_w -> bf16
            gemm_bt<<<dim3(Mg / 128, 6), 256, 0, stream>>>(xb, base, nullptr, 0, qkvb,
                                                           (int)Mg, 768, 256, 4, flagp);
            k_attn<<<dim3(2, 64, NB), 256, 0, stream>>>(qkvb, cpb + (long)l * 19208,
                                                        d_in[3], (long)l * 8, xb, (l & 1), flagp);
            // proj + LN1 + residual (fused)
            gemm_ln<<<dim3(Mg / 64), 256, 0, stream>>>(xb, base + 196608, d_in[9], (long)l * 256,
                                                       d_in[10], (long)l * 256, d_in[11], (long)l * 256,
                                                       xm + m0 * 256, xb, 256, flagp);
            // hidden = gelu(xb @ fw1 + fb1) -> bf16
            gemm_bt<<<dim3(Mg / 128, 8), 256, 0, stream>>>(xb, base + 262144, d_in[13], (long)l * 1024,
                                                           hid, (int)Mg, 1024, 256, 1 | 2 | 4, flagp);
            // fw2 + LN2 + residual (fused)
            gemm_ln<<<dim3(Mg / 64), 256, 0, stream>>>(hid, base + 524288, d_in[15], (long)l * 256,
                                                       d_in[16], (long)l * 256, d_in[17], (long)l * 256,
                                                       xm + m0 * 256, xb, 1024, flagp);
        }
    }
    k_final<<<dim3(NTOK_), 256, 0, stream>>>(xm, d_in[18], d_in[19], d_out, flagp);
}